// Round 5
// baseline (25.576 us; speedup 1.0000x reference)
//
#include <hip/hip_runtime.h>
#include <math.h>

typedef __attribute__((ext_vector_type(4))) float f32x4;
typedef __attribute__((ext_vector_type(2))) float f32x2;

__device__ __forceinline__ float rcpf(float x){ return __builtin_amdgcn_rcpf(x); }

#define HSTRIDE 66   // 64 + 2: f32x2 aligned, lanes l and l+16 share banks (2-way = free)

__global__ __launch_bounds__(512) void phys4(
    const float* __restrict__ x,
    const float* __restrict__ W1, const float* __restrict__ b1,
    const float* __restrict__ W2, const float* __restrict__ b2,
    const float* __restrict__ W3, const float* __restrict__ b3,
    const float* __restrict__ W4, const float* __restrict__ b4,
    const float* __restrict__ i0p, const float* __restrict__ alphap,
    float* __restrict__ out, int nrows)
{
    __shared__ float hbA[64*HSTRIDE];
    __shared__ float hbB[64*HSTRIDE];
    __shared__ __align__(16) float tab4[4000];   // [v][4] invbase per species
    __shared__ float latb[64*8];                 // [row][lat0..5,-,-]

    const int tid  = threadIdx.x;
    const int lane = tid & 63;     // = row within block during MLP phase
    const int wv   = tid >> 6;     // wave id 0..7 -> column slice [8wv, 8wv+8)
    const int c0   = 8*wv;

    // ---------------- prologue: voltage table ----------------
    {
        const float KFRT = (float)(96485.33/(8.314*298.15));
        const float dV = 1.25f/999.0f;
        float a0=alphap[0], a1=alphap[1], a2=alphap[2];
        float i00=i0p[0], i01=i0p[1], i02=i0p[2];
        for (int v = tid; v < 1000; v += 512){
            float Vv = -1.25f + (float)v*dV;
            tab4[v*4+0] = expf(a0*KFRT*(Vv+0.11f))/i00;
            tab4[v*4+1] = expf(a1*KFRT*(Vv-0.08f))/i01;
            tab4[v*4+2] = expf(a2*KFRT*(Vv))/i02;
            tab4[v*4+3] = 0.f;
        }
    }

    // ---------------- MLP phase: lane = row ----------------
    const int rowg = blockIdx.x*64 + lane;
    const int rowc = min(rowg, nrows-1);
    float xv[5];
#pragma unroll
    for (int i=0;i<5;i++) xv[i] = x[rowc*5+i];

    // L1: own 8-column slice, exact R1 nested-fmaf order (b + x0w0 + x1w1 + ...)
    float hs[8];
#pragma unroll
    for (int j=0;j<8;j++){
        int c = c0 + j;
        float h = b1[c];
        h = fmaf(xv[0], W1[0*64+c], h);
        h = fmaf(xv[1], W1[1*64+c], h);
        h = fmaf(xv[2], W1[2*64+c], h);
        h = fmaf(xv[3], W1[3*64+c], h);
        h = fmaf(xv[4], W1[4*64+c], h);
        hs[j] = fmaxf(h, 0.f);
    }

    float h[64];

#define EXCH(BUF)                                                        \
    {                                                                    \
        _Pragma("unroll")                                                \
        for (int q=0;q<4;q++){                                           \
            f32x2 t; t.x = hs[2*q]; t.y = hs[2*q+1];                     \
            *(f32x2*)&BUF[lane*HSTRIDE + c0 + 2*q] = t;                  \
        }                                                                \
        __syncthreads();                                                 \
        _Pragma("unroll")                                                \
        for (int q=0;q<32;q++){                                          \
            f32x2 t = *(const f32x2*)&BUF[lane*HSTRIDE + 2*q];           \
            h[2*q] = t.x; h[2*q+1] = t.y;                                \
        }                                                                \
    }

    // 64->64 layer: exact R1 4-accumulator pattern per column, k ascending
#define BIGLAYER(W, B)                                                   \
    {                                                                    \
        float A[4][8];                                                   \
        _Pragma("unroll")                                                \
        for (int j=0;j<8;j++){ A[0][j]=B[c0+j]; A[1][j]=0.f; A[2][j]=0.f; A[3][j]=0.f; } \
        _Pragma("unroll")                                                \
        for (int k=0;k<64;k++){                                          \
            f32x4 wa = *(const f32x4*)&W[k*64+c0];                       \
            f32x4 wb = *(const f32x4*)&W[k*64+c0+4];                     \
            A[k&3][0] = fmaf(h[k], wa.x, A[k&3][0]);                     \
            A[k&3][1] = fmaf(h[k], wa.y, A[k&3][1]);                     \
            A[k&3][2] = fmaf(h[k], wa.z, A[k&3][2]);                     \
            A[k&3][3] = fmaf(h[k], wa.w, A[k&3][3]);                     \
            A[k&3][4] = fmaf(h[k], wb.x, A[k&3][4]);                     \
            A[k&3][5] = fmaf(h[k], wb.y, A[k&3][5]);                     \
            A[k&3][6] = fmaf(h[k], wb.z, A[k&3][6]);                     \
            A[k&3][7] = fmaf(h[k], wb.w, A[k&3][7]);                     \
        }                                                                \
        _Pragma("unroll")                                                \
        for (int j=0;j<8;j++)                                            \
            hs[j] = fmaxf((A[0][j]+A[1][j])+(A[2][j]+A[3][j]), 0.f);     \
    }

    EXCH(hbA);            // h1 assembled
    BIGLAYER(W2, b2);     // -> h2 slice
    EXCH(hbB);            // h2 assembled
    BIGLAYER(W3, b3);     // -> h3 slice
    EXCH(hbA);            // h3 assembled (first-EXCH reads separated by hbB's barrier)

    // L4: waves 0..5 compute lat column c=wv for all rows; in-register halving
    // tree reproduces R1's butterfly lane-0 nesting exactly.
    if (wv < 6){
        float p[64];
#pragma unroll
        for (int k=0;k<64;k++) p[k] = h[k]*W4[k*6+wv];
#pragma unroll
        for (int off=32; off>0; off>>=1){
#pragma unroll
            for (int m=0;m<32;m++){
                if (m < off) p[m] += p[m+off];
            }
        }
        latb[lane*8+wv] = p[0] + b4[wv];
    }
    __syncthreads();

    // ---------------- search phase: 8 threads per row ----------------
    const int row = tid >> 3;        // 0..63
    const int cg  = tid & 7;
    const int rw  = (tid >> 3) & 7;  // row-group within wave
    const int rowg2 = blockIdx.x*64 + row;
    const int rowc2 = min(rowg2, nrows-1);

    const float lat0=latb[row*8+0], lat1=latb[row*8+1], lat2=latb[row*8+2];
    const float lat3=latb[row*8+3], lat4=latb[row*8+4], lat5=latb[row*8+5];
    const float x3 = x[rowc2*5+3];

    // epilogue constants (identical to R1)
    float rr   = 4e-8f * __expf(lat0);
    float epsv = rcpf(1.0f + __expf(-lat1));
    float Kdl  = __expf(lat2);
    float Deff = 1.91e-9f * epsv * sqrtf(epsv);
    float Kgdl = Kdl * Deff * rcpf(rr);
    float S    = rcpf(Kgdl) + fabsf(x3) * rcpf((1.0f - epsv) * Deff);
    float il0  = S * (float)(1.0 / (2.0  * 96485.33 * 34.0));
    float il1  = S * (float)(1.0 / (12.0 * 96485.33 * 34.0));

    float t0s = 2.0f*lat3, t1s = 2.0f*lat4, t2s = 2.0f*lat5;
    float mx = fmaxf(t0s, fmaxf(t1s, t2s));
    float e0 = __expf(t0s-mx), e1 = __expf(t1s-mx), e2 = __expf(t2s-mx);
    float se = e0 + e1 + e2;
    float it0 = se*rcpf(e0), it1 = se*rcpf(e1), it2 = se*rcpf(e2);

    auto itot = [&](int v) -> float {
        f32x4 tb = *(const f32x4*)&tab4[v*4];
        return rcpf(fmaf(tb.x, it0, il0)) + rcpf(fmaf(tb.y, it1, il1)) + rcpf(tb.z*it2);
    };

    // i_tot strictly decreasing in v (2%/step >> float noise).
    bool le0f = itot(0)   <= 200.0f;
    bool le9f = itot(999) <= 200.0f;

    int lo = 0, hi = 999;
#pragma unroll 1
    for (int rd = 0; rd < 3; ++rd){
        int L = hi - lo;
        int p = lo + (L*(cg+1))/9;
        bool le = itot(p) <= 200.0f;
        unsigned long long bal = __ballot(le);
        unsigned m8 = (unsigned)((bal >> (8*rw)) & 0xFFull);
        int tz  = (m8 == 0u) ? 8 : (int)__builtin_ctz(m8);
        int nlo = (tz > 0) ? lo + (L*tz)/9 : lo;
        int nhi = (tz < 8) ? lo + (L*(tz+1))/9 : hi;
        lo = nlo; hi = nhi;
    }
    // interval now <= 2 wide; one unconditional bisect step (no-op at width 1)
    {
        int mid = lo + ((hi-lo)>>1);
        bool lem = itot(mid) <= 200.0f;
        hi = lem ? mid : hi;
        lo = lem ? lo  : mid;
    }
    float da = itot(lo) - 200.0f;   // > 0 under invariant
    float db = 200.0f - itot(hi);   // >= 0
    int idx = (da <= db) ? lo : hi; // tie -> earlier index (argmin-first, = R1)
    if (!le9f) idx = 999;
    if (le0f)  idx = 0;

    f32x4 tb = *(const f32x4*)&tab4[idx*4];
    float s0 = rcpf(fmaf(tb.x, it0, il0));
    float s1 = rcpf(fmaf(tb.y, it1, il1));
    float s2 = rcpf(tb.z*it2);
    float inv = rcpf(s0 + s1 + s2);

    if (cg == 0 && rowg2 < nrows){
        float2 o; o.x = s1*inv; o.y = s0*inv;
        reinterpret_cast<float2*>(out)[rowg2] = o;
    }
}

extern "C" void kernel_launch(void* const* d_in, const int* in_sizes, int n_in,
                              void* d_out, int out_size, void* d_ws, size_t ws_size,
                              hipStream_t stream) {
    (void)n_in; (void)d_ws; (void)ws_size; (void)out_size;
    int nrows = in_sizes[0] / 5;
    int nblk = (nrows + 63) / 64;
    phys4<<<dim3(nblk), dim3(512), 0, stream>>>(
        (const float*)d_in[0],
        (const float*)d_in[1], (const float*)d_in[2],
        (const float*)d_in[3], (const float*)d_in[4],
        (const float*)d_in[5], (const float*)d_in[6],
        (const float*)d_in[7], (const float*)d_in[8],
        (const float*)d_in[9], (const float*)d_in[10],
        (float*)d_out, nrows);
}

// Round 6
// 14.679 us; speedup vs baseline: 1.7423x; 1.7423x over previous
//
#include <hip/hip_runtime.h>
#include <math.h>

typedef __attribute__((ext_vector_type(4))) float f32x4;

__device__ __forceinline__ float rcpf(float x){ return __builtin_amdgcn_rcpf(x); }

__global__ __launch_bounds__(512, 2) void phys5(
    const float* __restrict__ x,
    const float* __restrict__ W1, const float* __restrict__ b1,
    const float* __restrict__ W2, const float* __restrict__ b2,
    const float* __restrict__ W3, const float* __restrict__ b3,
    const float* __restrict__ W4, const float* __restrict__ b4,
    const float* __restrict__ i0p, const float* __restrict__ alphap,
    float* __restrict__ out, int nrows)
{
    __shared__ float hb[64*64];                 // [k][row] transposed hidden vector
    __shared__ __align__(16) float tab4[4000];  // [v][4] invbase per species
    __shared__ float latb[64*8];                // [row][lat0..5]

    const int tid  = threadIdx.x;
    const int lane = tid & 63;                              // row within block
    const int wvu  = __builtin_amdgcn_readfirstlane(tid >> 6);  // wave id, provably uniform
    const int c0u  = 8*wvu;                                 // column slice base (uniform)

    // ---------------- prologue: voltage table ----------------
    {
        const float KFRT = (float)(96485.33/(8.314*298.15));
        const float dV = 1.25f/999.0f;
        float a0=alphap[0], a1=alphap[1], a2=alphap[2];
        float i00=i0p[0], i01=i0p[1], i02=i0p[2];
        for (int v = tid; v < 1000; v += 512){
            float Vv = -1.25f + (float)v*dV;
            tab4[v*4+0] = expf(a0*KFRT*(Vv+0.11f))/i00;
            tab4[v*4+1] = expf(a1*KFRT*(Vv-0.08f))/i01;
            tab4[v*4+2] = expf(a2*KFRT*(Vv))/i02;
            tab4[v*4+3] = 0.f;
        }
    }

    // ---------------- MLP phase: lane = row, wave = 8-column slice ----------------
    const int rowg = blockIdx.x*64 + lane;
    const int rowc = min(rowg, nrows-1);
    float xv[5];
#pragma unroll
    for (int i=0;i<5;i++) xv[i] = x[rowc*5+i];

    // L1: exact R1 nested-fmaf order; weights via uniform (scalar) loads
    float hs[8];
#pragma unroll
    for (int j=0;j<8;j++){
        int c = c0u + j;
        float hv = b1[c];
        hv = fmaf(xv[0], W1[0*64+c], hv);
        hv = fmaf(xv[1], W1[1*64+c], hv);
        hv = fmaf(xv[2], W1[2*64+c], hv);
        hv = fmaf(xv[3], W1[3*64+c], hv);
        hv = fmaf(xv[4], W1[4*64+c], hv);
        hs[j] = fmaxf(hv, 0.f);
    }

    // publish h1 (transposed: conflict-free per-k reads later)
#pragma unroll
    for (int j=0;j<8;j++) hb[(c0u+j)*64 + lane] = hs[j];
    __syncthreads();

    // 64->64 layer: exact R1 4-accumulator pattern, k ascending.
    // h from LDS (per-lane row), weights from SGPRs (uniform s_load).
#define BIGLAYER(W, B)                                                   \
    {                                                                    \
        float A[4][8];                                                   \
        _Pragma("unroll")                                                \
        for (int j=0;j<8;j++){ A[0][j]=B[c0u+j]; A[1][j]=0.f; A[2][j]=0.f; A[3][j]=0.f; } \
        _Pragma("unroll 16")                                             \
        for (int k=0;k<64;k++){                                          \
            float hk = hb[k*64 + lane];                                  \
            _Pragma("unroll")                                            \
            for (int j=0;j<8;j++)                                        \
                A[k&3][j] = fmaf(hk, W[k*64 + c0u + j], A[k&3][j]);      \
        }                                                                \
        _Pragma("unroll")                                                \
        for (int j=0;j<8;j++)                                            \
            hs[j] = fmaxf((A[0][j]+A[1][j])+(A[2][j]+A[3][j]), 0.f);     \
    }

    BIGLAYER(W2, b2);          // h2 slice
    __syncthreads();           // all waves done reading h1
#pragma unroll
    for (int j=0;j<8;j++) hb[(c0u+j)*64 + lane] = hs[j];
    __syncthreads();

    BIGLAYER(W3, b3);          // h3 slice
    __syncthreads();           // all waves done reading h2
#pragma unroll
    for (int j=0;j<8;j++) hb[(c0u+j)*64 + lane] = hs[j];
    __syncthreads();

    // L4: waves 0..5 compute lat column wv for all rows; halving tree
    // reproduces R1's butterfly lane-0 nesting exactly (mul then adds).
    if (wvu < 6){
        float p[64];
#pragma unroll
        for (int k=0;k<64;k++) p[k] = hb[k*64 + lane] * W4[k*6 + wvu];
#pragma unroll
        for (int off=32; off>0; off>>=1){
#pragma unroll
            for (int m=0;m<32;m++){
                if (m < off) p[m] += p[m+off];
            }
        }
        latb[lane*8+wvu] = p[0] + b4[wvu];
    }
    __syncthreads();

    // ---------------- search phase: 8 threads per row ----------------
    const int row = tid >> 3;        // 0..63
    const int cg  = tid & 7;
    const int rw  = (tid >> 3) & 7;  // row-group within wave
    const int rowg2 = blockIdx.x*64 + row;
    const int rowc2 = min(rowg2, nrows-1);

    const float lat0=latb[row*8+0], lat1=latb[row*8+1], lat2=latb[row*8+2];
    const float lat3=latb[row*8+3], lat4=latb[row*8+4], lat5=latb[row*8+5];
    const float x3 = x[rowc2*5+3];

    // epilogue constants (identical to R1)
    float rr   = 4e-8f * __expf(lat0);
    float epsv = rcpf(1.0f + __expf(-lat1));
    float Kdl  = __expf(lat2);
    float Deff = 1.91e-9f * epsv * sqrtf(epsv);
    float Kgdl = Kdl * Deff * rcpf(rr);
    float S    = rcpf(Kgdl) + fabsf(x3) * rcpf((1.0f - epsv) * Deff);
    float il0  = S * (float)(1.0 / (2.0  * 96485.33 * 34.0));
    float il1  = S * (float)(1.0 / (12.0 * 96485.33 * 34.0));

    float t0s = 2.0f*lat3, t1s = 2.0f*lat4, t2s = 2.0f*lat5;
    float mx = fmaxf(t0s, fmaxf(t1s, t2s));
    float e0 = __expf(t0s-mx), e1 = __expf(t1s-mx), e2 = __expf(t2s-mx);
    float se = e0 + e1 + e2;
    float it0 = se*rcpf(e0), it1 = se*rcpf(e1), it2 = se*rcpf(e2);

    auto itot = [&](int v) -> float {
        f32x4 tb = *(const f32x4*)&tab4[v*4];
        return rcpf(fmaf(tb.x, it0, il0)) + rcpf(fmaf(tb.y, it1, il1)) + rcpf(tb.z*it2);
    };

    // i_tot strictly decreasing in v (2%/step >> float noise).
    bool le0f = itot(0)   <= 200.0f;
    bool le9f = itot(999) <= 200.0f;

    int lo = 0, hi = 999;
#pragma unroll 1
    for (int rd = 0; rd < 3; ++rd){
        int L = hi - lo;
        int p = lo + (L*(cg+1))/9;
        bool le = itot(p) <= 200.0f;
        unsigned long long bal = __ballot(le);
        unsigned m8 = (unsigned)((bal >> (8*rw)) & 0xFFull);
        int tz  = (m8 == 0u) ? 8 : (int)__builtin_ctz(m8);
        int nlo = (tz > 0) ? lo + (L*tz)/9 : lo;
        int nhi = (tz < 8) ? lo + (L*(tz+1))/9 : hi;
        lo = nlo; hi = nhi;
    }
    // interval now <= 2 wide; one unconditional bisect step (no-op at width 1)
    {
        int mid = lo + ((hi-lo)>>1);
        bool lem = itot(mid) <= 200.0f;
        hi = lem ? mid : hi;
        lo = lem ? lo  : mid;
    }
    float da = itot(lo) - 200.0f;   // > 0 under invariant
    float db = 200.0f - itot(hi);   // >= 0
    int idx = (da <= db) ? lo : hi; // tie -> earlier index (argmin-first, = R1)
    if (!le9f) idx = 999;
    if (le0f)  idx = 0;

    f32x4 tb = *(const f32x4*)&tab4[idx*4];
    float s0 = rcpf(fmaf(tb.x, it0, il0));
    float s1 = rcpf(fmaf(tb.y, it1, il1));
    float s2 = rcpf(tb.z*it2);
    float inv = rcpf(s0 + s1 + s2);

    if (cg == 0 && rowg2 < nrows){
        float2 o; o.x = s1*inv; o.y = s0*inv;
        reinterpret_cast<float2*>(out)[rowg2] = o;
    }
}

extern "C" void kernel_launch(void* const* d_in, const int* in_sizes, int n_in,
                              void* d_out, int out_size, void* d_ws, size_t ws_size,
                              hipStream_t stream) {
    (void)n_in; (void)d_ws; (void)ws_size; (void)out_size;
    int nrows = in_sizes[0] / 5;
    int nblk = (nrows + 63) / 64;
    phys5<<<dim3(nblk), dim3(512), 0, stream>>>(
        (const float*)d_in[0],
        (const float*)d_in[1], (const float*)d_in[2],
        (const float*)d_in[3], (const float*)d_in[4],
        (const float*)d_in[5], (const float*)d_in[6],
        (const float*)d_in[7], (const float*)d_in[8],
        (const float*)d_in[9], (const float*)d_in[10],
        (float*)d_out, nrows);
}

// Round 7
// 14.455 us; speedup vs baseline: 1.7694x; 1.0155x over previous
//
#include <hip/hip_runtime.h>
#include <math.h>

typedef __attribute__((ext_vector_type(4))) float f32x4;

__device__ __forceinline__ float rcpf(float x){ return __builtin_amdgcn_rcpf(x); }

__global__ __launch_bounds__(1024, 4) void phys6(
    const float* __restrict__ x,
    const float* __restrict__ W1, const float* __restrict__ b1,
    const float* __restrict__ W2, const float* __restrict__ b2,
    const float* __restrict__ W3, const float* __restrict__ b3,
    const float* __restrict__ W4, const float* __restrict__ b4,
    const float* __restrict__ i0p, const float* __restrict__ alphap,
    float* __restrict__ out, int nrows)
{
    __shared__ float hb[64*64];                 // [k][row] transposed hidden vector
    __shared__ __align__(16) float tab4[4000];  // [v][4] invbase per species
    __shared__ float latb[64*8];                // [row][lat0..5, x3, -]

    const int tid  = threadIdx.x;
    const int lane = tid & 63;                                  // row within block
    const int wvu  = __builtin_amdgcn_readfirstlane(tid >> 6);  // wave id 0..15 (uniform)
    const int c0u  = 4*wvu;                                     // 4-column slice base

    // ---------------- prologue: voltage table ----------------
    {
        const float KFRT = (float)(96485.33/(8.314*298.15));
        const float dV = 1.25f/999.0f;
        float a0=alphap[0], a1=alphap[1], a2=alphap[2];
        float i00=i0p[0], i01=i0p[1], i02=i0p[2];
        for (int v = tid; v < 1000; v += 1024){
            float Vv = -1.25f + (float)v*dV;
            tab4[v*4+0] = expf(a0*KFRT*(Vv+0.11f))/i00;
            tab4[v*4+1] = expf(a1*KFRT*(Vv-0.08f))/i01;
            tab4[v*4+2] = expf(a2*KFRT*(Vv))/i02;
            tab4[v*4+3] = 0.f;
        }
    }

    // ---------------- MLP phase: lane = row, wave = 4-column slice ----------------
    const int rowg = blockIdx.x*64 + lane;
    const int rowc = min(rowg, nrows-1);
    float xv[5];
#pragma unroll
    for (int i=0;i<5;i++) xv[i] = x[rowc*5+i];
    if (wvu == 6) latb[lane*8+6] = xv[3];       // stash x3 for the search phase

    // L1: exact nested-fmaf order; weights via uniform (scalar) loads
    float hs[4];
#pragma unroll
    for (int j=0;j<4;j++){
        int c = c0u + j;
        float hv = b1[c];
        hv = fmaf(xv[0], W1[0*64+c], hv);
        hv = fmaf(xv[1], W1[1*64+c], hv);
        hv = fmaf(xv[2], W1[2*64+c], hv);
        hv = fmaf(xv[3], W1[3*64+c], hv);
        hv = fmaf(xv[4], W1[4*64+c], hv);
        hs[j] = fmaxf(hv, 0.f);
    }

    // publish h1 transposed (conflict-free: lanes write consecutive addresses)
#pragma unroll
    for (int j=0;j<4;j++) hb[(c0u+j)*64 + lane] = hs[j];
    __syncthreads();

    // 64->64 layer: per-column A[k&3] accumulator rotation, k ascending.
    // h from LDS (per-lane), weights s_load_dwordx4 (64 SGPRs per unroll-16 window).
#define BIGLAYER(W, B)                                                   \
    {                                                                    \
        float A[4][4];                                                   \
        _Pragma("unroll")                                                \
        for (int j=0;j<4;j++){ A[0][j]=B[c0u+j]; A[1][j]=0.f; A[2][j]=0.f; A[3][j]=0.f; } \
        _Pragma("unroll 16")                                             \
        for (int k=0;k<64;k++){                                          \
            float hk = hb[k*64 + lane];                                  \
            _Pragma("unroll")                                            \
            for (int j=0;j<4;j++)                                        \
                A[k&3][j] = fmaf(hk, W[k*64 + c0u + j], A[k&3][j]);      \
        }                                                                \
        _Pragma("unroll")                                                \
        for (int j=0;j<4;j++)                                            \
            hs[j] = fmaxf((A[0][j]+A[1][j])+(A[2][j]+A[3][j]), 0.f);     \
    }

    BIGLAYER(W2, b2);          // h2 slice
    __syncthreads();           // all waves done reading h1
#pragma unroll
    for (int j=0;j<4;j++) hb[(c0u+j)*64 + lane] = hs[j];
    __syncthreads();

    BIGLAYER(W3, b3);          // h3 slice
    __syncthreads();           // all waves done reading h2
#pragma unroll
    for (int j=0;j<4;j++) hb[(c0u+j)*64 + lane] = hs[j];
    __syncthreads();

    // L4: waves 0..5 compute lat column wvu for all rows; halving tree
    // reproduces the butterfly's lane-0 reduction nesting exactly.
    if (wvu < 6){
        float p[64];
#pragma unroll
        for (int k=0;k<64;k++) p[k] = hb[k*64 + lane] * W4[k*6 + wvu];
#pragma unroll
        for (int off=32; off>0; off>>=1){
#pragma unroll
            for (int m=0;m<32;m++){
                if (m < off) p[m] += p[m+off];
            }
        }
        latb[lane*8+wvu] = p[0] + b4[wvu];
    }
    __syncthreads();

    // ---------------- search phase: 8 threads per row (waves 0..7) ----------------
    if (tid >= 512) return;    // no barriers below

    const int row = tid >> 3;        // 0..63
    const int cg  = tid & 7;
    const int rw  = (tid >> 3) & 7;  // row-group within wave
    const int rowg2 = blockIdx.x*64 + row;

    const float lat0=latb[row*8+0], lat1=latb[row*8+1], lat2=latb[row*8+2];
    const float lat3=latb[row*8+3], lat4=latb[row*8+4], lat5=latb[row*8+5];
    const float x3 = latb[row*8+6];

    // epilogue constants
    float rr   = 4e-8f * __expf(lat0);
    float epsv = rcpf(1.0f + __expf(-lat1));
    float Kdl  = __expf(lat2);
    float Deff = 1.91e-9f * epsv * sqrtf(epsv);
    float Kgdl = Kdl * Deff * rcpf(rr);
    float S    = rcpf(Kgdl) + fabsf(x3) * rcpf((1.0f - epsv) * Deff);
    float il0  = S * (float)(1.0 / (2.0  * 96485.33 * 34.0));
    float il1  = S * (float)(1.0 / (12.0 * 96485.33 * 34.0));

    float t0s = 2.0f*lat3, t1s = 2.0f*lat4, t2s = 2.0f*lat5;
    float mx = fmaxf(t0s, fmaxf(t1s, t2s));
    float e0 = __expf(t0s-mx), e1 = __expf(t1s-mx), e2 = __expf(t2s-mx);
    float se = e0 + e1 + e2;
    float it0 = se*rcpf(e0), it1 = se*rcpf(e1), it2 = se*rcpf(e2);

    auto itot = [&](int v) -> float {
        f32x4 tb = *(const f32x4*)&tab4[v*4];
        return rcpf(fmaf(tb.x, it0, il0)) + rcpf(fmaf(tb.y, it1, il1)) + rcpf(tb.z*it2);
    };

    // i_tot strictly decreasing in v (2%/step >> float noise).
    bool le0f = itot(0)   <= 200.0f;
    bool le9f = itot(999) <= 200.0f;

    int lo = 0, hi = 999;
#pragma unroll 1
    for (int rd = 0; rd < 3; ++rd){
        int L = hi - lo;
        int p = lo + (L*(cg+1))/9;
        bool le = itot(p) <= 200.0f;
        unsigned long long bal = __ballot(le);
        unsigned m8 = (unsigned)((bal >> (8*rw)) & 0xFFull);
        int tz  = (m8 == 0u) ? 8 : (int)__builtin_ctz(m8);
        int nlo = (tz > 0) ? lo + (L*tz)/9 : lo;
        int nhi = (tz < 8) ? lo + (L*(tz+1))/9 : hi;
        lo = nlo; hi = nhi;
    }
    // interval now <= 2 wide; one unconditional bisect step (no-op at width 1)
    {
        int mid = lo + ((hi-lo)>>1);
        bool lem = itot(mid) <= 200.0f;
        hi = lem ? mid : hi;
        lo = lem ? lo  : mid;
    }
    float da = itot(lo) - 200.0f;   // > 0 under invariant
    float db = 200.0f - itot(hi);   // >= 0
    int idx = (da <= db) ? lo : hi; // tie -> earlier index (argmin-first)
    if (!le9f) idx = 999;
    if (le0f)  idx = 0;

    f32x4 tb = *(const f32x4*)&tab4[idx*4];
    float s0 = rcpf(fmaf(tb.x, it0, il0));
    float s1 = rcpf(fmaf(tb.y, it1, il1));
    float s2 = rcpf(tb.z*it2);
    float inv = rcpf(s0 + s1 + s2);

    if (cg == 0 && rowg2 < nrows){
        float2 o; o.x = s1*inv; o.y = s0*inv;
        reinterpret_cast<float2*>(out)[rowg2] = o;
    }
}

extern "C" void kernel_launch(void* const* d_in, const int* in_sizes, int n_in,
                              void* d_out, int out_size, void* d_ws, size_t ws_size,
                              hipStream_t stream) {
    (void)n_in; (void)d_ws; (void)ws_size; (void)out_size;
    int nrows = in_sizes[0] / 5;
    int nblk = (nrows + 63) / 64;
    phys6<<<dim3(nblk), dim3(1024), 0, stream>>>(
        (const float*)d_in[0],
        (const float*)d_in[1], (const float*)d_in[2],
        (const float*)d_in[3], (const float*)d_in[4],
        (const float*)d_in[5], (const float*)d_in[6],
        (const float*)d_in[7], (const float*)d_in[8],
        (const float*)d_in[9], (const float*)d_in[10],
        (float*)d_out, nrows);
}